// Round 1
// baseline (620.888 us; speedup 1.0000x reference)
//
#include <hip/hip_runtime.h>

// Problem constants (from reference)
constexpr int B = 256, L = 500, D = 3, C = 32, I = 35, H = 512, O = 15, M = 5, J = 35;

// -------------------------------------------------------------------------
// Kernel 1: c[l,h,b] = sum_i x[l,b,i] * W_enc[l,i,h]   (stored TRANSPOSED: [L][H][B])
// Tile: one block = (l, 64 h, 64 b), 256 threads, 4x4 per thread, K=35.
// -------------------------------------------------------------------------
__global__ __launch_bounds__(256) void k1_c(const float* __restrict__ inp,
                                            const float* __restrict__ z,
                                            const float* __restrict__ W,
                                            float* __restrict__ cT) {
  const int l  = blockIdx.x;
  const int h0 = blockIdx.y * 64;
  const int b0 = blockIdx.z * 64;
  __shared__ __align__(16) float Xs[I][68];  // Xs[i][b_local], pad 68 (16B-aligned rows)
  __shared__ __align__(16) float Ws[I][68];  // Ws[i][h_local]
  const int tid = threadIdx.x;

  for (int idx = tid; idx < 64 * I; idx += 256) {
    int bl = idx / I, i = idx % I;
    int b = b0 + bl;
    Xs[i][bl] = (i < D) ? inp[(b * L + l) * D + i] : z[(b * L + l) * C + (i - D)];
  }
  for (int idx = tid; idx < I * 64; idx += 256) {
    int i = idx / 64, hl = idx % 64;
    Ws[i][hl] = W[(l * I + i) * H + h0 + hl];
  }
  __syncthreads();

  const int tb = tid & 15;   // 16 groups of 4 b  (lane-minor -> coalesced stores)
  const int th = tid >> 4;   // 16 groups of 4 h
  float acc[4][4] = {};
#pragma unroll
  for (int k = 0; k < I; ++k) {
    float4 wv = *(const float4*)&Ws[k][th * 4];
    float4 xv = *(const float4*)&Xs[k][tb * 4];
    float w[4] = {wv.x, wv.y, wv.z, wv.w};
    float x[4] = {xv.x, xv.y, xv.z, xv.w};
#pragma unroll
    for (int hr = 0; hr < 4; ++hr)
#pragma unroll
      for (int br = 0; br < 4; ++br) acc[hr][br] = fmaf(w[hr], x[br], acc[hr][br]);
  }
#pragma unroll
  for (int hr = 0; hr < 4; ++hr) {
    float4 v = {acc[hr][0], acc[hr][1], acc[hr][2], acc[hr][3]};
    *(float4*)&cT[((size_t)l * H + h0 + th * 4 + hr) * B + b0 + tb * 4] = v;
  }
}

// -------------------------------------------------------------------------
// Kernel 2: in-place exclusive scan over l per (h,b):  h[l] = relu(b_enc[h] + sum_{j<l} c[j])
// One thread per (h,b); lanes consecutive in b -> coalesced. Manual 4-unroll
// groups independent loads ahead of stores.
// -------------------------------------------------------------------------
__global__ __launch_bounds__(256) void k2_scan(float* __restrict__ cT,
                                               const float* __restrict__ benc) {
  const int t = blockIdx.x * 256 + threadIdx.x;  // t < H*B
  const int h = t >> 8;                          // B == 256
  const int b = t & 255;
  const float be = benc[h];
  const size_t stride = (size_t)H * B;
  size_t idx = (size_t)h * B + b;
  float run = 0.f;
  for (int l = 0; l < L; l += 4) {
    float v0 = cT[idx + 0 * stride];
    float v1 = cT[idx + 1 * stride];
    float v2 = cT[idx + 2 * stride];
    float v3 = cT[idx + 3 * stride];
    cT[idx + 0 * stride] = fmaxf(run + be, 0.f); run += v0;
    cT[idx + 1 * stride] = fmaxf(run + be, 0.f); run += v1;
    cT[idx + 2 * stride] = fmaxf(run + be, 0.f); run += v2;
    cT[idx + 3 * stride] = fmaxf(run + be, 0.f); run += v3;
    idx += 4 * stride;
  }
}

// -------------------------------------------------------------------------
// Kernel 3: out[b,l,j] = sum_h hT[l,h,b] * Vcat[l,h,j] + bias[l,j]
// One block per l, thread = b. V/bias addresses are wave-uniform -> s_load.
// h staged via LDS with coalesced float4 loads; output staged via LDS for
// coalesced stores.
// -------------------------------------------------------------------------
__global__ __launch_bounds__(256) void k3_proj(const float* __restrict__ hT,
                                               const float* __restrict__ Vmu,
                                               const float* __restrict__ bmu,
                                               const float* __restrict__ Vsg,
                                               const float* __restrict__ bsg,
                                               const float* __restrict__ Vpi,
                                               const float* __restrict__ bpi,
                                               float* __restrict__ out) {
  const int l = blockIdx.x;
  const int tid = threadIdx.x;
  __shared__ __align__(16) float hs[16][B];
  __shared__ __align__(16) float outs[B][J];

  float acc[J];
#pragma unroll
  for (int j = 0; j < J; ++j) acc[j] = 0.f;

  for (int k0 = 0; k0 < H; k0 += 16) {
    __syncthreads();
#pragma unroll
    for (int t = 0; t < 4; ++t) {           // 16 rows x 256 floats, float4 each
      int f = tid + t * 256;                 // float4 index in tile
      int i = f >> 6, c = (f & 63) * 4;
      *(float4*)&hs[i][c] = *(const float4*)&hT[((size_t)l * H + k0 + i) * B + c];
    }
    __syncthreads();
#pragma unroll 4
    for (int k = 0; k < 16; ++k) {
      float hv = hs[k][tid];
      int kk = k0 + k;
      const float* vm = &Vmu[((size_t)l * H + kk) * O];
      const float* vs = &Vsg[((size_t)l * H + kk) * O];
      const float* vp = &Vpi[((size_t)l * H + kk) * M];
#pragma unroll
      for (int j = 0; j < O; ++j) acc[j] = fmaf(hv, vm[j], acc[j]);
#pragma unroll
      for (int j = 0; j < O; ++j) acc[O + j] = fmaf(hv, vs[j], acc[O + j]);
#pragma unroll
      for (int j = 0; j < M; ++j) acc[2 * O + j] = fmaf(hv, vp[j], acc[2 * O + j]);
    }
  }

#pragma unroll
  for (int j = 0; j < O; ++j) acc[j] += bmu[l * O + j];
#pragma unroll
  for (int j = 0; j < O; ++j) acc[O + j] += bsg[l * O + j];
#pragma unroll
  for (int j = 0; j < M; ++j) acc[2 * O + j] += bpi[l * M + j];

#pragma unroll
  for (int j = 0; j < J; ++j) outs[tid][j] = acc[j];  // row stride 35 (odd) -> conflict-free
  __syncthreads();
  for (int idx = tid; idx < B * J; idx += 256) {
    int b = idx / J, j = idx % J;
    out[((size_t)b * L + l) * J + j] = outs[b][j];
  }
}

extern "C" void kernel_launch(void* const* d_in, const int* in_sizes, int n_in,
                              void* d_out, int out_size, void* d_ws, size_t ws_size,
                              hipStream_t stream) {
  const float* inp  = (const float*)d_in[0];
  const float* z    = (const float*)d_in[1];
  const float* Wenc = (const float*)d_in[2];
  const float* benc = (const float*)d_in[3];
  const float* Vmu  = (const float*)d_in[4];
  const float* bmu  = (const float*)d_in[5];
  const float* Vsg  = (const float*)d_in[6];
  const float* bsg  = (const float*)d_in[7];
  const float* Vpi  = (const float*)d_in[8];
  const float* bpi  = (const float*)d_in[9];
  float* out = (float*)d_out;
  float* cT  = (float*)d_ws;  // [L][H][B] fp32 = 262.1 MB scratch (c, then h in-place)

  dim3 g1(L, H / 64, B / 64);
  k1_c<<<g1, 256, 0, stream>>>(inp, z, Wenc, cT);
  k2_scan<<<dim3((H * B) / 256), 256, 0, stream>>>(cT, benc);
  k3_proj<<<dim3(L), 256, 0, stream>>>(cT, Vmu, bmu, Vsg, bsg, Vpi, bpi, out);
}

// Round 2
// 356.551 us; speedup vs baseline: 1.7414x; 1.7414x over previous
//
#include <hip/hip_runtime.h>

// Problem constants (from reference)
constexpr int B = 256, L = 500, D = 3, C = 32, I = 35, H = 512, O = 15, M = 5, J = 35;

typedef __attribute__((ext_vector_type(8))) short short8;  // 8 x bf16 (4 VGPRs), MFMA A/B frag
typedef __attribute__((ext_vector_type(4))) float f32x4;   // MFMA C/D frag

__device__ __forceinline__ unsigned int bf16rne(float f) {
  unsigned int u = __float_as_uint(f);
  return (u + 0x7FFFu + ((u >> 16) & 1u)) >> 16;  // round-to-nearest-even, low 16 bits valid
}
__device__ __forceinline__ float bf16tof(unsigned short s) {
  return __uint_as_float(((unsigned int)s) << 16);
}

// -------------------------------------------------------------------------
// Kernel 1: c[l,b,h] = sum_i x[l,b,i] * W_enc[l,i,h], stored bf16 [L][B][H].
// Block = (l, 64-h chunk) covering ALL 256 b -> W chunk read exactly once.
// Thread: 4 b x 16 h. h is lane-minor -> 128B-contiguous bf16 stores.
// -------------------------------------------------------------------------
__global__ __launch_bounds__(256) void k1_c(const float* __restrict__ inp,
                                            const float* __restrict__ z,
                                            const float* __restrict__ W,
                                            unsigned short* __restrict__ cBH) {
  const int l  = blockIdx.x;
  const int h0 = blockIdx.y * 64;
  __shared__ __align__(16) float Xs[I][260];  // [i][b], pad 260 keeps 16B rows
  __shared__ __align__(16) float Ws[I][64];   // [i][h_local]
  const int tid = threadIdx.x;

  for (int idx = tid; idx < B * I; idx += 256) {
    int b = idx / I, i = idx - b * I;
    Xs[i][b] = (i < D) ? inp[(b * L + l) * D + i] : z[(b * L + l) * C + (i - D)];
  }
  for (int idx = tid; idx < I * 64; idx += 256) {
    int i = idx >> 6, hl = idx & 63;
    Ws[i][hl] = W[((size_t)l * I + i) * H + h0 + hl];
  }
  __syncthreads();

  const int th = tid & 3;   // h group of 16 (lane-minor)
  const int tb = tid >> 2;  // b group of 4
  float acc[4][16] = {};
#pragma unroll
  for (int k = 0; k < I; ++k) {
    float4 xv = *(const float4*)&Xs[k][tb * 4];
    float x[4] = {xv.x, xv.y, xv.z, xv.w};
    const float* wr = &Ws[k][th * 16];
#pragma unroll
    for (int c = 0; c < 4; ++c) {
      float4 wv = *(const float4*)&wr[c * 4];
      float w[4] = {wv.x, wv.y, wv.z, wv.w};
#pragma unroll
      for (int br = 0; br < 4; ++br)
#pragma unroll
        for (int hh = 0; hh < 4; ++hh)
          acc[br][c * 4 + hh] = fmaf(x[br], w[hh], acc[br][c * 4 + hh]);
    }
  }
#pragma unroll
  for (int br = 0; br < 4; ++br) {
    const int b = tb * 4 + br;
    uint4 p0, p1;
    p0.x = bf16rne(acc[br][0])  | (bf16rne(acc[br][1])  << 16);
    p0.y = bf16rne(acc[br][2])  | (bf16rne(acc[br][3])  << 16);
    p0.z = bf16rne(acc[br][4])  | (bf16rne(acc[br][5])  << 16);
    p0.w = bf16rne(acc[br][6])  | (bf16rne(acc[br][7])  << 16);
    p1.x = bf16rne(acc[br][8])  | (bf16rne(acc[br][9])  << 16);
    p1.y = bf16rne(acc[br][10]) | (bf16rne(acc[br][11]) << 16);
    p1.z = bf16rne(acc[br][12]) | (bf16rne(acc[br][13]) << 16);
    p1.w = bf16rne(acc[br][14]) | (bf16rne(acc[br][15]) << 16);
    unsigned short* dst = &cBH[((size_t)l * B + b) * H + h0 + th * 16];
    *(uint4*)dst = p0;
    *(uint4*)(dst + 8) = p1;
  }
}

// -------------------------------------------------------------------------
// Kernel 2: in-place exclusive scan over l per (b,h): h[l]=relu(b_enc+sum_{j<l}c[j])
// fp32 running sum; bf16 load/store. 10-deep unroll -> 10 loads in flight.
// -------------------------------------------------------------------------
__global__ __launch_bounds__(256) void k2_scan(unsigned short* __restrict__ cBH,
                                               const float* __restrict__ benc) {
  const int t = blockIdx.x * 256 + threadIdx.x;  // flat over B*H, h-minor (coalesced)
  const int h = t & (H - 1);
  const float be = benc[h];
  const size_t stride = (size_t)B * H;
  size_t idx = (size_t)t;
  float run = 0.f;
#pragma unroll 1
  for (int l = 0; l < L; l += 10) {
    unsigned short v[10];
#pragma unroll
    for (int j = 0; j < 10; ++j) v[j] = cBH[idx + j * stride];
#pragma unroll
    for (int j = 0; j < 10; ++j) {
      cBH[idx + j * stride] = (unsigned short)bf16rne(fmaxf(run + be, 0.f));
      run += bf16tof(v[j]);
    }
    idx += 10 * stride;
  }
}

// -------------------------------------------------------------------------
// Kernel 3: out[b,l,:] = h[l,b,:] @ [V_mu|V_sigma|V_pi][l] + bias, via bf16 MFMA.
// One block per l (4 waves). V transposed fp32->bf16 into LDS [j][k] once
// (rows padded 520 -> 2-way-max bank aliasing); barrier-free K-loop; A-frags
// (h) stream from global bf16 [b][h] as short8. N padded 35->48 (3 n-tiles).
// -------------------------------------------------------------------------
__global__ __launch_bounds__(256) void k3_proj(const unsigned short* __restrict__ hBH,
                                               const float* __restrict__ Vmu,
                                               const float* __restrict__ bmu,
                                               const float* __restrict__ Vsg,
                                               const float* __restrict__ bsg,
                                               const float* __restrict__ Vpi,
                                               const float* __restrict__ bpi,
                                               float* __restrict__ out) {
  const int l = blockIdx.x;
  const int tid = threadIdx.x;
  __shared__ __align__(16) unsigned short Vs[48][520];  // [j][k] bf16, padded
  __shared__ float biasS[48];

  for (int idx = tid; idx < H * O; idx += 256) {
    int k = idx / O, j = idx - k * O;
    Vs[j][k]     = (unsigned short)bf16rne(Vmu[(size_t)l * H * O + idx]);
    Vs[O + j][k] = (unsigned short)bf16rne(Vsg[(size_t)l * H * O + idx]);
  }
  for (int idx = tid; idx < H * M; idx += 256) {
    int k = idx / M, j = idx - k * M;
    Vs[2 * O + j][k] = (unsigned short)bf16rne(Vpi[(size_t)l * H * M + idx]);
  }
  for (int idx = tid; idx < 13 * 520; idx += 256) {  // zero pad rows 35..47
    int r = idx / 520, c = idx - r * 520;
    Vs[J + r][c] = 0;
  }
  if (tid < 48) {
    float bv = 0.f;
    if (tid < O)          bv = bmu[l * O + tid];
    else if (tid < 2 * O) bv = bsg[l * O + tid - O];
    else if (tid < J)     bv = bpi[l * M + tid - 2 * O];
    biasS[tid] = bv;
  }
  __syncthreads();

  const int wave = tid >> 6, lane = tid & 63;
  const int m0 = wave * 64;          // 4 m-tiles of 16 b per wave
  const int row16 = lane & 15, quad = lane >> 4;
  f32x4 acc[4][3];
#pragma unroll
  for (int mt = 0; mt < 4; ++mt)
#pragma unroll
    for (int nt = 0; nt < 3; ++nt) acc[mt][nt] = (f32x4){0.f, 0.f, 0.f, 0.f};

  const unsigned short* Abase = hBH + (size_t)l * B * H;
#pragma unroll 1
  for (int kt = 0; kt < 16; ++kt) {  // K = 512 in steps of 32
    const int k0 = kt * 32 + quad * 8;
    short8 a[4], bb[3];
#pragma unroll
    for (int mt = 0; mt < 4; ++mt)
      a[mt] = *(const short8*)&Abase[(size_t)(m0 + mt * 16 + row16) * H + k0];
#pragma unroll
    for (int nt = 0; nt < 3; ++nt)
      bb[nt] = *(const short8*)&Vs[nt * 16 + row16][k0];
#pragma unroll
    for (int mt = 0; mt < 4; ++mt)
#pragma unroll
      for (int nt = 0; nt < 3; ++nt)
        acc[mt][nt] = __builtin_amdgcn_mfma_f32_16x16x32_bf16(a[mt], bb[nt], acc[mt][nt], 0, 0, 0);
  }

  // Epilogue: D layout col=lane&15 (j), row=quad*4+reg (b). Skip padded j>=35.
#pragma unroll
  for (int nt = 0; nt < 3; ++nt) {
    const int j = nt * 16 + row16;
    if (j < J) {
      const float bias = biasS[j];
#pragma unroll
      for (int mt = 0; mt < 4; ++mt) {
#pragma unroll
        for (int r = 0; r < 4; ++r) {
          const int b = m0 + mt * 16 + quad * 4 + r;
          out[((size_t)b * L + l) * J + j] = acc[mt][nt][r] + bias;
        }
      }
    }
  }
}

extern "C" void kernel_launch(void* const* d_in, const int* in_sizes, int n_in,
                              void* d_out, int out_size, void* d_ws, size_t ws_size,
                              hipStream_t stream) {
  const float* inp  = (const float*)d_in[0];
  const float* z    = (const float*)d_in[1];
  const float* Wenc = (const float*)d_in[2];
  const float* benc = (const float*)d_in[3];
  const float* Vmu  = (const float*)d_in[4];
  const float* bmu  = (const float*)d_in[5];
  const float* Vsg  = (const float*)d_in[6];
  const float* bsg  = (const float*)d_in[7];
  const float* Vpi  = (const float*)d_in[8];
  const float* bpi  = (const float*)d_in[9];
  float* out = (float*)d_out;
  unsigned short* cBH = (unsigned short*)d_ws;  // bf16 [L][B][H] = 131 MB (c, then h in-place)

  k1_c<<<dim3(L, H / 64), 256, 0, stream>>>(inp, z, Wenc, cBH);
  k2_scan<<<dim3((B * H) / 256), 256, 0, stream>>>(cBH, benc);
  k3_proj<<<dim3(L), 256, 0, stream>>>(cBH, Vmu, bmu, Vsg, bsg, Vpi, bpi, out);
}